// Round 2
// baseline (595.518 us; speedup 1.0000x reference)
//
#include <hip/hip_runtime.h>
#include <hip/hip_bf16.h>

// Problem constants
#define NROWS 8192   // rows of x / out
#define IN_F  4096   // K
#define OUT_F 4096   // output features

typedef __attribute__((ext_vector_type(8))) __bf16 bf16x8;
typedef __attribute__((ext_vector_type(4))) float  f32x4;

// ---------------------------------------------------------------------------
// Static device scratch (avoids any dependence on d_ws / ws_size).
// Fully rewritten on every kernel_launch call.
// ---------------------------------------------------------------------------
__device__ double g_sum;                            // |w| sum accumulator
__device__ ushort g_wq[(size_t)OUT_F * IN_F];       // 32 MiB ternary bf16 codes
__device__ ushort g_xb[(size_t)NROWS * IN_F];       // 64 MiB x in bf16

// ---------------------------------------------------------------------------
// Kernel 0: zero the accumulator (1 thread; replaces hipMemsetAsync)
// ---------------------------------------------------------------------------
__global__ void tl_zero_sum() { g_sum = 0.0; }

// ---------------------------------------------------------------------------
// Kernel 1: sum |w| in fp64 (grid-stride float4, wave shuffle + block reduce,
// one double atomicAdd per block).
// ---------------------------------------------------------------------------
__global__ void tl_reduce_abs(const float* __restrict__ w, int n4) {
    double local = 0.0;
    int idx = blockIdx.x * blockDim.x + threadIdx.x;
    int stride = gridDim.x * blockDim.x;
    const float4* w4 = (const float4*)w;
    for (int i = idx; i < n4; i += stride) {
        float4 v = w4[i];
        local += (double)fabsf(v.x) + (double)fabsf(v.y) +
                 (double)fabsf(v.z) + (double)fabsf(v.w);
    }
    // wave-64 reduction
    for (int off = 32; off > 0; off >>= 1)
        local += __shfl_down(local, off, 64);
    __shared__ double ssum[4];
    int lane = threadIdx.x & 63, wv = threadIdx.x >> 6;
    if (lane == 0) ssum[wv] = local;
    __syncthreads();
    if (threadIdx.x == 0) {
        double t = ssum[0] + ssum[1] + ssum[2] + ssum[3];
        atomicAdd(&g_sum, t);
    }
}

// ---------------------------------------------------------------------------
// Kernel 2: ternary-quantize w -> bf16 codes {0xBF80, 0, 0x3F80}
// ---------------------------------------------------------------------------
__global__ void tl_quantize_w(const float* __restrict__ w, int n4) {
    const float thresh = (float)(0.5 * g_sum / (double)((size_t)OUT_F * IN_F));
    int idx = blockIdx.x * blockDim.x + threadIdx.x;
    int stride = gridDim.x * blockDim.x;
    const float4* w4 = (const float4*)w;
    ushort4* q4 = (ushort4*)g_wq;
    for (int i = idx; i < n4; i += stride) {
        float4 v = w4[i];
        ushort4 q;
        q.x = v.x > thresh ? 0x3F80u : (v.x < -thresh ? 0xBF80u : 0u);
        q.y = v.y > thresh ? 0x3F80u : (v.y < -thresh ? 0xBF80u : 0u);
        q.z = v.z > thresh ? 0x3F80u : (v.z < -thresh ? 0xBF80u : 0u);
        q.w = v.w > thresh ? 0x3F80u : (v.w < -thresh ? 0xBF80u : 0u);
        q4[i] = q;
    }
}

// ---------------------------------------------------------------------------
// Kernel 3: x fp32 -> bf16 (RNE)
// ---------------------------------------------------------------------------
__device__ inline ushort f2bf_rne(float f) {
    unsigned u = __builtin_bit_cast(unsigned, f);
    unsigned r = u + 0x7FFFu + ((u >> 16) & 1u);
    return (ushort)(r >> 16);
}

__global__ void tl_cvt_x(const float* __restrict__ x, int n4) {
    int idx = blockIdx.x * blockDim.x + threadIdx.x;
    int stride = gridDim.x * blockDim.x;
    const float4* x4 = (const float4*)x;
    ushort4* o4 = (ushort4*)g_xb;
    for (int i = idx; i < n4; i += stride) {
        float4 v = x4[i];
        ushort4 q;
        q.x = f2bf_rne(v.x);
        q.y = f2bf_rne(v.y);
        q.z = f2bf_rne(v.z);
        q.w = f2bf_rne(v.w);
        o4[i] = q;
    }
}

// ---------------------------------------------------------------------------
// Kernel 4: GEMM  C[m,n] = (sum_k A[m,k]*B[n,k] + bias[n]) * gamma
// A = g_xb [M,K] bf16, B = g_wq [N,K] bf16 (both K-major => gemm_bt).
// 128x128 block tile, BK=32, 256 threads (4 waves, 2x2 of 64x64),
// global_load_lds width-16 staging, ds_read_b128 fragments,
// mfma_f32_16x16x32_bf16 4x4 per wave.
// ---------------------------------------------------------------------------
#define GLD_LDS(gp, lp) \
    __builtin_amdgcn_global_load_lds( \
        (const __attribute__((address_space(1))) void*)(gp), \
        (__attribute__((address_space(3))) void*)(lp), 16, 0, 0)

__global__ __launch_bounds__(256) void tl_gemm_bt(
    const float* __restrict__ bias,
    const float* __restrict__ gamma_p,
    float* __restrict__ C) {
    constexpr int K = IN_F, N = OUT_F;
    constexpr int BK = 32;

    const ushort* __restrict__ A = g_xb;
    const ushort* __restrict__ B = g_wq;

    // LDS tiles, chunk-contiguous layout: element (row,k) at row*BK + k.
    // Chunk c (16 B = 8 bf16) lands at byte c*16 -> matches the wave-uniform
    // base + lane*16 scatter of global_load_lds. NO padding allowed.
    __shared__ __align__(16) ushort As[128 * BK];
    __shared__ __align__(16) ushort Bs[128 * BK];

    const int tid  = threadIdx.x;
    const int lane = tid & 63;
    const int wave = tid >> 6;
    const int wm = (wave >> 1) * 64;   // wave row offset inside 128x128 tile
    const int wn = (wave & 1) * 64;    // wave col offset

    const int rowBase = blockIdx.y * 128;   // M
    const int colBase = blockIdx.x * 128;   // N

    f32x4 acc[4][4] = {};

    // chunk ids this thread stages: c0 = tid, c1 = 256 + tid
    const int c0 = tid, c1 = 256 + tid;
    const int r0 = c0 >> 2, cc0 = (c0 & 3) * 8;
    const int r1 = c1 >> 2, cc1 = (c1 & 3) * 8;

    const ushort* A0 = A + (size_t)(rowBase + r0) * K + cc0;
    const ushort* A1 = A + (size_t)(rowBase + r1) * K + cc1;
    const ushort* B0 = B + (size_t)(colBase + r0) * K + cc0;
    const ushort* B1 = B + (size_t)(colBase + r1) * K + cc1;

    char* lA = (char*)As;
    char* lB = (char*)Bs;
    const int lo0 = (wave * 64) * 16;          // wave-uniform LDS byte base, i=0
    const int lo1 = (256 + wave * 64) * 16;    // i=1

    const int kq  = (lane >> 4) * 8;   // k offset of this lane's fragment
    const int r16 = lane & 15;         // row-in-16 of this lane's fragment

    for (int kt = 0; kt < K; kt += BK) {
        GLD_LDS(A0 + kt, lA + lo0);
        GLD_LDS(A1 + kt, lA + lo1);
        GLD_LDS(B0 + kt, lB + lo0);
        GLD_LDS(B1 + kt, lB + lo1);
        __syncthreads();   // drains vmcnt -> LDS tiles complete

        bf16x8 af[4], bf[4];
#pragma unroll
        for (int i = 0; i < 4; ++i) {
            af[i] = *(const bf16x8*)(As + (wm + i * 16 + r16) * BK + kq);
            bf[i] = *(const bf16x8*)(Bs + (wn + i * 16 + r16) * BK + kq);
        }
#pragma unroll
        for (int im = 0; im < 4; ++im)
#pragma unroll
            for (int in = 0; in < 4; ++in)
                acc[im][in] = __builtin_amdgcn_mfma_f32_16x16x32_bf16(
                    af[im], bf[in], acc[im][in], 0, 0, 0);
        __syncthreads();   // all waves done reading before next overwrite
    }

    // Epilogue. C/D layout: col = lane&15, row = (lane>>4)*4 + reg.
    const float g = *gamma_p;
    const int cq = (lane >> 4) * 4;
#pragma unroll
    for (int in = 0; in < 4; ++in) {
        const int col = colBase + wn + in * 16 + (lane & 15);
        const float bv = bias[col];
#pragma unroll
        for (int im = 0; im < 4; ++im) {
            const int rowb = rowBase + wm + im * 16 + cq;
#pragma unroll
            for (int r = 0; r < 4; ++r) {
                C[(size_t)(rowb + r) * N + col] = (acc[im][in][r] + bv) * g;
            }
        }
    }
}

// ---------------------------------------------------------------------------
// Launch. No d_ws usage at all — all scratch is static __device__ globals.
// ---------------------------------------------------------------------------
extern "C" void kernel_launch(void* const* d_in, const int* in_sizes, int n_in,
                              void* d_out, int out_size, void* d_ws, size_t ws_size,
                              hipStream_t stream) {
    const float* x     = (const float*)d_in[0];
    const float* w     = (const float*)d_in[1];
    const float* bias  = (const float*)d_in[2];
    const float* gamma = (const float*)d_in[3];
    float* out = (float*)d_out;
    (void)d_ws; (void)ws_size;

    tl_zero_sum<<<1, 1, 0, stream>>>();
    tl_reduce_abs<<<1024, 256, 0, stream>>>(w, OUT_F * IN_F / 4);
    tl_quantize_w<<<1024, 256, 0, stream>>>(w, OUT_F * IN_F / 4);
    tl_cvt_x<<<2048, 256, 0, stream>>>(x, NROWS * IN_F / 4);

    dim3 grid(OUT_F / 128, NROWS / 128);
    tl_gemm_bt<<<grid, 256, 0, stream>>>(bias, gamma, out);
}